// Round 1
// 4727.394 us; speedup vs baseline: 1.8177x; 1.8177x over previous
//
#include <hip/hip_runtime.h>
#include <cstdint>
#include <cstddef>

// Model constants
static constexpr int kD   = 768;
static constexpr int kHD  = 64;
static constexpr int kNH  = 12;
static constexpr int kT   = 512;
static constexpr int kB   = 4;
static constexpr int kRows = kB * kT;        // 2048
static constexpr int kV   = 50257;
static constexpr int kL   = 6;
static constexpr int kFF  = 3072;
static constexpr float kEps = 1e-5f;

typedef short bf16x8 __attribute__((ext_vector_type(8)));
typedef float f32x4  __attribute__((ext_vector_type(4)));
typedef unsigned short u16;
typedef unsigned short u16x4 __attribute__((ext_vector_type(4)));
typedef unsigned short u16x8 __attribute__((ext_vector_type(8)));

// ---------------------------------------------------------------------------
// fp32 -> bf16 hi/lo split:  a ~= hi + lo,  |err| <= 2^-17 |a|
// hi = truncate(a) to bf16 (exact top 16 bits); lo = RNE(a - hi)
// ---------------------------------------------------------------------------
__device__ __forceinline__ void split1(float a, u16& h, u16& l)
{
    unsigned u = __float_as_uint(a);
    h = (u16)(u >> 16);
    float fh = __uint_as_float(u & 0xFFFF0000u);
    float r = a - fh;                       // exact in fp32
    unsigned v = __float_as_uint(r);
    l = (u16)((v + 0x7FFFu + ((v >> 16) & 1u)) >> 16);
}

// ---------------------------------------------------------------------------
// Embedding: x[row,d] = tok_emb[ids[row], d] + pos_emb[row % T, d]
// ---------------------------------------------------------------------------
__global__ __launch_bounds__(256) void embed_kernel(
    const int* __restrict__ ids, const float* __restrict__ tok,
    const float* __restrict__ pos, float* __restrict__ x)
{
    int i = blockIdx.x * 256 + threadIdx.x;
    if (i >= kRows * kD) return;
    int row = i / kD, d = i - row * kD;
    x[i] = tok[(size_t)ids[row] * kD + d] + pos[(row % kT) * kD + d];
}

// ---------------------------------------------------------------------------
// LayerNorm: one block (256 threads) per row of 768
// ---------------------------------------------------------------------------
__global__ __launch_bounds__(256) void ln_kernel(
    const float* __restrict__ x, const float* __restrict__ g,
    const float* __restrict__ b, float* __restrict__ o)
{
    const int row = blockIdx.x;
    const float* xr = x + (size_t)row * kD;
    float s = 0.f, ss = 0.f;
    for (int d = threadIdx.x; d < kD; d += 256) {
        float v = xr[d];
        s += v; ss += v * v;
    }
    #pragma unroll
    for (int off = 32; off; off >>= 1) {
        s  += __shfl_xor(s, off);
        ss += __shfl_xor(ss, off);
    }
    __shared__ float sh_s[4], sh_ss[4];
    const int wid = threadIdx.x >> 6, lane = threadIdx.x & 63;
    if (lane == 0) { sh_s[wid] = s; sh_ss[wid] = ss; }
    __syncthreads();
    s  = sh_s[0] + sh_s[1] + sh_s[2] + sh_s[3];
    ss = sh_ss[0] + sh_ss[1] + sh_ss[2] + sh_ss[3];
    const float mean = s * (1.0f / kD);
    const float var  = ss * (1.0f / kD) - mean * mean;
    const float rstd = rsqrtf(var + kEps);
    float* orow = o + (size_t)row * kD;
    for (int d = threadIdx.x; d < kD; d += 256)
        orow[d] = (xr[d] - mean) * rstd * g[d] + b[d];
}

// ---------------------------------------------------------------------------
// Elementwise fp32 -> (bf16 hi, bf16 lo) split. n multiple of 1024; grid n/1024.
// ---------------------------------------------------------------------------
__global__ __launch_bounds__(256) void split_kernel(
    const float* __restrict__ in, u16* __restrict__ hi, u16* __restrict__ lo)
{
    const int i = blockIdx.x * 256 + threadIdx.x;
    float4 v = ((const float4*)in)[i];
    u16x4 hv, lv;
    u16 a, c;
    split1(v.x, a, c); hv[0] = a; lv[0] = c;
    split1(v.y, a, c); hv[1] = a; lv[1] = c;
    split1(v.z, a, c); hv[2] = a; lv[2] = c;
    split1(v.w, a, c); hv[3] = a; lv[3] = c;
    ((u16x4*)hi)[i] = hv;
    ((u16x4*)lo)[i] = lv;
}

// ---------------------------------------------------------------------------
// Repack per-layer QKV weights (H,D,HD each) into W [768 x 2304] and bias[2304]
// ---------------------------------------------------------------------------
__global__ __launch_bounds__(256) void repack_qkv_kernel(
    const float* __restrict__ wk, const float* __restrict__ wq,
    const float* __restrict__ wv, const float* __restrict__ bk,
    const float* __restrict__ bq, const float* __restrict__ bv,
    float* __restrict__ Wp, float* __restrict__ Bp)
{
    int i = blockIdx.x * 256 + threadIdx.x;
    if (i < 3 * kD) {
        int which = i / kD, c = i - which * kD;
        const float* bsrc = (which == 0) ? bk : (which == 1) ? bq : bv;
        Bp[i] = bsrc[c];
    }
    if (i >= kD * 3 * kD) return;
    int col = i % (3 * kD), d = i / (3 * kD);
    int which = col / kD, hc = col - which * kD;   // hc = h*64+e
    const float* src = (which == 0) ? wk : (which == 1) ? wq : wv;
    Wp[i] = src[(size_t)(hc >> 6) * (kD * kHD) + (size_t)d * kHD + (hc & 63)];
}

// ---------------------------------------------------------------------------
// bf16x3 MFMA GEMM: out[M,N] = A[M,K] @ W[K,N] (+bias)(+resid)(relu?)
//   A pre-split into Ahi/Alo bf16 [M][K] (row-major, K contiguous).
//   W fp32 [K][N], split in-kernel during LDS staging.
//   Tile BM x 128, BK=32, 256 threads (4 waves, each owns (BM/2) x 64).
//   3 MFMA passes per fragment pair: hi*hi + hi*lo + lo*hi (err ~2^-17).
// Fragment layout (guide-verified, mfma_f32_16x16x32_bf16):
//   A/B: lane holds 8 contiguous k at row/col = lane&15, k0 = 8*(lane>>4)
//   C/D: col = lane&15, row = 4*(lane>>4) + reg
// ---------------------------------------------------------------------------
template<int BM>
__global__ __launch_bounds__(256) void gemm3_kernel(
    const u16* __restrict__ Ahi, const u16* __restrict__ Alo,
    const float* __restrict__ W, const float* __restrict__ bias,
    const float* __restrict__ resid, float* __restrict__ out,
    int N, int K, int relu)
{
    constexpr int LDT = 40;                // 32 + 8 pad (keeps 16B align, ~2-way banks)
    __shared__ u16 Ah[BM][LDT], Al[BM][LDT];
    __shared__ u16 Bh[128][LDT], Bl[128][LDT];
    const int tid = threadIdx.x;
    const int m0 = blockIdx.y * BM;
    const int n0 = blockIdx.x * 128;
    const int wid = tid >> 6, lane = tid & 63;
    const int wr = wid >> 1, wc = wid & 1;     // wave quadrant
    const int fr = lane & 15, fg = lane >> 4;  // frag row/col, k-group
    constexpr int MF = BM / 32;                // m-frags per wave

    f32x4 acc[MF][4];
    #pragma unroll
    for (int i = 0; i < MF; ++i)
        #pragma unroll
        for (int j = 0; j < 4; ++j) acc[i][j] = (f32x4){0.f, 0.f, 0.f, 0.f};

    const int bc  = tid >> 1;              // B col 0..127
    const int bk0 = (tid & 1) << 4;        // k sub-offset 0 / 16
    const bool bvalid = (n0 + bc) < N;

    for (int k0 = 0; k0 < K; k0 += 32) {
        // ---- stage A (pre-split bf16, vector copies)
        for (int i = tid; i < BM * 4; i += 256) {
            const int r = i >> 2, q = (i & 3) << 3;
            const size_t off = (size_t)(m0 + r) * K + k0 + q;
            *(u16x8*)&Ah[r][q] = *(const u16x8*)(Ahi + off);
            *(u16x8*)&Al[r][q] = *(const u16x8*)(Alo + off);
        }
        // ---- stage B: 16 coalesced fp32 loads per thread, split, write K-contig
        {
            const float* wp = W + (size_t)(k0 + bk0) * N + (n0 + bc);
            float v[16];
            #pragma unroll
            for (int j = 0; j < 16; ++j)
                v[j] = bvalid ? wp[(size_t)j * N] : 0.f;
            #pragma unroll
            for (int j4 = 0; j4 < 4; ++j4) {
                u16x4 hh, ll;
                #pragma unroll
                for (int j = 0; j < 4; ++j) {
                    u16 h1, l1; split1(v[(j4 << 2) + j], h1, l1);
                    hh[j] = h1; ll[j] = l1;
                }
                *(u16x4*)&Bh[bc][bk0 + (j4 << 2)] = hh;
                *(u16x4*)&Bl[bc][bk0 + (j4 << 2)] = ll;
            }
        }
        __syncthreads();

        bf16x8 ah[MF], al[MF], bh[4], bl[4];
        #pragma unroll
        for (int f = 0; f < MF; ++f) {
            const int row = wr * (BM / 2) + (f << 4) + fr;
            ah[f] = *(const bf16x8*)&Ah[row][fg << 3];
            al[f] = *(const bf16x8*)&Al[row][fg << 3];
        }
        #pragma unroll
        for (int f = 0; f < 4; ++f) {
            const int col = (wc << 6) + (f << 4) + fr;
            bh[f] = *(const bf16x8*)&Bh[col][fg << 3];
            bl[f] = *(const bf16x8*)&Bl[col][fg << 3];
        }
        #pragma unroll
        for (int i = 0; i < MF; ++i)
            #pragma unroll
            for (int j = 0; j < 4; ++j) {
                acc[i][j] = __builtin_amdgcn_mfma_f32_16x16x32_bf16(ah[i], bh[j], acc[i][j], 0, 0, 0);
                acc[i][j] = __builtin_amdgcn_mfma_f32_16x16x32_bf16(ah[i], bl[j], acc[i][j], 0, 0, 0);
                acc[i][j] = __builtin_amdgcn_mfma_f32_16x16x32_bf16(al[i], bh[j], acc[i][j], 0, 0, 0);
            }
        __syncthreads();
    }

    // ---- epilogue: C/D layout col=lane&15, row=4*(lane>>4)+reg
    #pragma unroll
    for (int i = 0; i < MF; ++i) {
        const int mb = m0 + wr * (BM / 2) + (i << 4) + (fg << 2);
        #pragma unroll
        for (int j = 0; j < 4; ++j) {
            const int n = n0 + (wc << 6) + (j << 4) + fr;
            if (n < N) {
                const float bvv = bias ? bias[n] : 0.f;
                #pragma unroll
                for (int r = 0; r < 4; ++r) {
                    const size_t oo = (size_t)(mb + r) * N + n;
                    float vv = acc[i][j][r] + bvv;
                    if (resid) vv += resid[oo];
                    if (relu)  vv = fmaxf(vv, 0.f);
                    out[oo] = vv;
                }
            }
        }
    }
}

// ---------------------------------------------------------------------------
// Tiled flash-style attention. One block (256 thr) per (b, h, 64 t-rows).
// Quirk preserved: wei[t][s] = k_t . q_s (K indexes output rows), no scaling.
// K-block transposed in LDS once; per s-tile stage Q^T + V; 4x4 per-thread
// score & PV passes; online softmax with 16-lane shuffle row-reduces.
// V and P tiles XOR-swizzled (quad granularity) to avoid stride-64 conflicts.
// LDS = 4 * 16 KiB = 64 KiB exactly.
// ---------------------------------------------------------------------------
__global__ __launch_bounds__(256) void attn2_kernel(
    const float* __restrict__ qkv, float* __restrict__ out)
{
    __shared__ float KbT[64][64];
    __shared__ float QbT[64][64];
    __shared__ float Vb[64][64];
    __shared__ float Pt[64][64];
    const int tb = gridDim.x - 1 - blockIdx.x;   // heavy blocks first
    const int hh = blockIdx.y, b = blockIdx.z;
    const int t0 = tb << 6;
    const int tid = threadIdx.x;
    const int ty = tid >> 4, tx = tid & 15;
    const int sr = tid >> 2;                 // staging row 0..63
    const int se0 = (tid & 3) << 4;          // staging e-offset 0/16/32/48
    const size_t rb = (size_t)b * kT;

    {   // stage K transposed: KbT[e][t]
        const float* ks = qkv + (rb + t0 + sr) * (3 * kD) + hh * kHD + se0;
        #pragma unroll
        for (int j = 0; j < 16; j += 4) {
            float4 v = *(const float4*)(ks + j);
            KbT[se0 + j + 0][sr] = v.x;
            KbT[se0 + j + 1][sr] = v.y;
            KbT[se0 + j + 2][sr] = v.z;
            KbT[se0 + j + 3][sr] = v.w;
        }
    }

    float m[4], l[4], O[4][4];
    #pragma unroll
    for (int i = 0; i < 4; ++i) {
        m[i] = -INFINITY; l[i] = 0.f;
        #pragma unroll
        for (int j = 0; j < 4; ++j) O[i][j] = 0.f;
    }

    for (int s0 = 0; s0 <= t0; s0 += 64) {
        __syncthreads();   // protect QbT/Vb/Pt reuse (and first-iter KbT)
        {   // stage Q transposed + V (swizzled quads)
            const float* qs = qkv + (rb + s0 + sr) * (3 * kD) + kD + hh * kHD + se0;
            #pragma unroll
            for (int j = 0; j < 16; j += 4) {
                float4 v = *(const float4*)(qs + j);
                QbT[se0 + j + 0][sr] = v.x;
                QbT[se0 + j + 1][sr] = v.y;
                QbT[se0 + j + 2][sr] = v.z;
                QbT[se0 + j + 3][sr] = v.w;
            }
            const float* vs = qkv + (rb + s0 + sr) * (3 * kD) + 2 * kD + hh * kHD + se0;
            #pragma unroll
            for (int jq = 0; jq < 4; ++jq) {
                const int c4 = (se0 >> 2) + jq;
                *(float4*)&Vb[sr][(c4 ^ (sr & 15)) << 2] = *(const float4*)(vs + (jq << 2));
            }
        }
        __syncthreads();

        // scores S[t=4ty+i][s=4tx+j] = sum_e K[t][e] * Q[s][e]
        float S[4][4];
        #pragma unroll
        for (int i = 0; i < 4; ++i)
            #pragma unroll
            for (int j = 0; j < 4; ++j) S[i][j] = 0.f;

        #pragma unroll 8
        for (int e = 0; e < 64; ++e) {
            float4 ka = *(const float4*)&KbT[e][ty << 2];
            float4 qa = *(const float4*)&QbT[e][tx << 2];
            float a[4] = {ka.x, ka.y, ka.z, ka.w};
            float q[4] = {qa.x, qa.y, qa.z, qa.w};
            #pragma unroll
            for (int i = 0; i < 4; ++i)
                #pragma unroll
                for (int j = 0; j < 4; ++j)
                    S[i][j] = fmaf(a[i], q[j], S[i][j]);
        }

        if (s0 == t0) {   // causal mask on the diagonal tile: keep s <= t
            #pragma unroll
            for (int i = 0; i < 4; ++i)
                #pragma unroll
                for (int j = 0; j < 4; ++j)
                    if (((tx << 2) + j) > ((ty << 2) + i)) S[i][j] = -INFINITY;
        }

        // online softmax (row state replicated across the 16 tx lanes)
        float p[4][4];
        #pragma unroll
        for (int i = 0; i < 4; ++i) {
            float mx = fmaxf(fmaxf(S[i][0], S[i][1]), fmaxf(S[i][2], S[i][3]));
            #pragma unroll
            for (int off = 1; off < 16; off <<= 1)
                mx = fmaxf(mx, __shfl_xor(mx, off));
            const float nm = fmaxf(m[i], mx);
            const float sc = __expf(m[i] - nm);
            float rs = 0.f;
            #pragma unroll
            for (int j = 0; j < 4; ++j) { p[i][j] = __expf(S[i][j] - nm); rs += p[i][j]; }
            #pragma unroll
            for (int off = 1; off < 16; off <<= 1) rs += __shfl_xor(rs, off);
            l[i] = l[i] * sc + rs;
            m[i] = nm;
            #pragma unroll
            for (int j = 0; j < 4; ++j) O[i][j] *= sc;
        }
        // write P transposed: Pt[s][t] (swizzled quads)
        #pragma unroll
        for (int j = 0; j < 4; ++j) {
            const int scol = (tx << 2) + j;
            float4 pv = make_float4(p[0][j], p[1][j], p[2][j], p[3][j]);
            *(float4*)&Pt[scol][(ty ^ (scol & 15)) << 2] = pv;
        }
        __syncthreads();

        // O[t][d] += sum_s P[t][s] * V[s][d]
        #pragma unroll 8
        for (int s = 0; s < 64; ++s) {
            float4 pa = *(const float4*)&Pt[s][(ty ^ (s & 15)) << 2];
            float4 va = *(const float4*)&Vb[s][(tx ^ (s & 15)) << 2];
            float a[4] = {pa.x, pa.y, pa.z, pa.w};
            float v[4] = {va.x, va.y, va.z, va.w};
            #pragma unroll
            for (int i = 0; i < 4; ++i)
                #pragma unroll
                for (int j = 0; j < 4; ++j)
                    O[i][j] = fmaf(a[i], v[j], O[i][j]);
        }
    }

    #pragma unroll
    for (int i = 0; i < 4; ++i) {
        const float inv = 1.0f / l[i];
        float4 o4 = make_float4(O[i][0] * inv, O[i][1] * inv, O[i][2] * inv, O[i][3] * inv);
        *(float4*)&out[(rb + t0 + (ty << 2) + i) * kD + hh * kHD + (tx << 2)] = o4;
    }
}

// ---------------------------------------------------------------------------
// Loss: one block per row; logsumexp over V, nll = logZ - logit[target]
// ---------------------------------------------------------------------------
__global__ __launch_bounds__(256) void loss_kernel(
    const float* __restrict__ logits, const int* __restrict__ target,
    float* __restrict__ loss)
{
    const int row = blockIdx.x;
    const float* lr = logits + (size_t)row * kV;
    const int wid = threadIdx.x >> 6, lane = threadIdx.x & 63;
    __shared__ float red[4];

    float lmax = -INFINITY;
    for (int i = threadIdx.x; i < kV; i += 256) lmax = fmaxf(lmax, lr[i]);
    #pragma unroll
    for (int off = 32; off; off >>= 1) lmax = fmaxf(lmax, __shfl_xor(lmax, off));
    if (lane == 0) red[wid] = lmax;
    __syncthreads();
    lmax = fmaxf(fmaxf(red[0], red[1]), fmaxf(red[2], red[3]));
    __syncthreads();

    float lsum = 0.f;
    for (int i = threadIdx.x; i < kV; i += 256) lsum += __expf(lr[i] - lmax);
    #pragma unroll
    for (int off = 32; off; off >>= 1) lsum += __shfl_xor(lsum, off);
    if (lane == 0) red[wid] = lsum;
    __syncthreads();
    lsum = red[0] + red[1] + red[2] + red[3];

    if (threadIdx.x == 0) {
        float logZ = lmax + logf(lsum);
        float nll = logZ - lr[target[row]];
        atomicAdd(loss, nll * (1.0f / kRows));
    }
}

// ---------------------------------------------------------------------------
extern "C" void kernel_launch(void* const* d_in, const int* in_sizes, int n_in,
                              void* d_out, int out_size, void* d_ws, size_t ws_size,
                              hipStream_t stream)
{
    const int*   ids = (const int*)d_in[0];
    const int*   tgt = (const int*)d_in[1];
    const float* tok = (const float*)d_in[2];
    const float* pos = (const float*)d_in[3];
    const float* ipw = (const float*)d_in[4];
    const float* ipb = (const float*)d_in[5];
    const float* wk  = (const float*)d_in[6];
    const float* bk  = (const float*)d_in[7];
    const float* wq  = (const float*)d_in[8];
    const float* bq  = (const float*)d_in[9];
    const float* wv  = (const float*)d_in[10];
    const float* bv  = (const float*)d_in[11];
    const float* opw = (const float*)d_in[12];
    const float* opb = (const float*)d_in[13];
    const float* fw1 = (const float*)d_in[14];
    const float* fb1 = (const float*)d_in[15];
    const float* fw2 = (const float*)d_in[16];
    const float* fb2 = (const float*)d_in[17];
    const float* lag = (const float*)d_in[18];
    const float* lab = (const float*)d_in[19];
    const float* lfg = (const float*)d_in[20];
    const float* lfb = (const float*)d_in[21];
    const float* outw = (const float*)d_in[22];
    const float* outb = (const float*)d_in[23];

    float* ws = (float*)d_ws;
    const size_t S = (size_t)kRows * kD;          // 1,572,864 floats
    float* x    = ws;                  // [S]
    float* h    = x    + S;            // [S]
    float* h2   = h    + S;            // [S]
    float* atb  = h2   + S;            // [S]
    float* qkv  = atb  + S;            // [3S]
    float* ffh  = qkv  + 3 * S;        // [4S]
    float* wqkv = ffh  + 4 * S;        // [768*2304]
    float* bqkv = wqkv + (size_t)kD * 3 * kD;

    // bf16 split scratch aliased onto dead fp32 regions (no extra workspace):
    u16* sfA_hi = (u16*)ffh;  u16* sfA_lo = sfA_hi + S;       // in ffh (S elems each)
    u16* sqA_hi = (u16*)qkv;  u16* sqA_lo = sqA_hi + S;       // in qkv (post-attn)
    u16* sbA_hi = (u16*)h2;   u16* sbA_lo = sbA_hi + 4 * S;   // spans h2..qkv (4S each)
    u16* shA_hi = (u16*)h;    u16* shA_lo = shA_hi + S;       // in h (logits stage)

    float* logits = (float*)d_out;
    float* loss = logits + (size_t)kRows * kV;

    embed_kernel<<<(kRows * kD + 255) / 256, 256, 0, stream>>>(ids, tok, pos, x);

    const size_t wsz = (size_t)kD * kD;
    const size_t fsz = (size_t)kD * kFF;
    const int splitS = (int)(S / 1024);            // 1536 blocks
    for (int l = 0; l < kL; ++l) {
        ln_kernel<<<kRows, 256, 0, stream>>>(x, lag + l * kD, lab + l * kD, h);
        split_kernel<<<splitS, 256, 0, stream>>>(h, sfA_hi, sfA_lo);
        gemm3_kernel<64><<<dim3(6, 32), 256, 0, stream>>>(
            sfA_hi, sfA_lo, ipw + l * wsz, ipb + l * kD, nullptr, h2, kD, kD, 0);
        repack_qkv_kernel<<<(kD * 3 * kD + 255) / 256, 256, 0, stream>>>(
            wk + l * wsz, wq + l * wsz, wv + l * wsz,
            bk + l * kD, bq + l * kD, bv + l * kD, wqkv, bqkv);
        split_kernel<<<splitS, 256, 0, stream>>>(h2, sfA_hi, sfA_lo);
        gemm3_kernel<128><<<dim3(18, 16), 256, 0, stream>>>(
            sfA_hi, sfA_lo, wqkv, bqkv, nullptr, qkv, 3 * kD, kD, 0);
        attn2_kernel<<<dim3(kT / 64, kNH, kB), 256, 0, stream>>>(qkv, atb);
        split_kernel<<<splitS, 256, 0, stream>>>(atb, sfA_hi, sfA_lo);
        gemm3_kernel<64><<<dim3(6, 32), 256, 0, stream>>>(
            sfA_hi, sfA_lo, opw + l * wsz, opb + l * kD, x, x, kD, kD, 0);
        ln_kernel<<<kRows, 256, 0, stream>>>(x, lfg + l * kD, lfb + l * kD, h);
        split_kernel<<<splitS, 256, 0, stream>>>(h, sqA_hi, sqA_lo);
        gemm3_kernel<128><<<dim3(24, 16), 256, 0, stream>>>(
            sqA_hi, sqA_lo, fw1 + l * fsz, fb1 + l * kFF, nullptr, ffh, kFF, kD, 1);
        split_kernel<<<4 * splitS, 256, 0, stream>>>(ffh, sbA_hi, sbA_lo);
        gemm3_kernel<64><<<dim3(6, 32), 256, 0, stream>>>(
            sbA_hi, sbA_lo, fw2 + l * fsz, fb2 + l * kD, x, x, kD, kFF, 0);
    }
    split_kernel<<<splitS, 256, 0, stream>>>(x, shA_hi, shA_lo);
    gemm3_kernel<128><<<dim3((kV + 127) / 128, 16), 256, 0, stream>>>(
        shA_hi, shA_lo, outw, outb, nullptr, logits, kV, kD, 0);
    hipMemsetAsync(loss, 0, sizeof(float), stream);
    loss_kernel<<<kRows, 256, 0, stream>>>(logits, tgt, loss);
}